// Round 4
// baseline (453.435 us; speedup 1.0000x reference)
//
#include <hip/hip_runtime.h>
#include <cstdint>

#define EPS 1e-6f

constexpr int Bsz = 4, Hn = 16, Lseq = 8192, Dd = 64;
constexpr int BH = Bsz * Hn;              // 64
constexpr int CHUNK = 64;                 // rows per wave-chunk (= 64 lanes: 1 mask row/lane)
constexpr int CPB = Lseq / CHUNK;         // 128 chunks per (b,h)
constexpr int NCHUNKS = BH * CPB;         // 8192
constexpr int WPB = 4;                    // waves per block
constexpr int NBLK = NCHUNKS / WPB;       // 2048 blocks
constexpr int QCH = CPB / 4;              // 32 chunks per scan-quarter

// feature map: x>0 ? x+1 : exp(x). __expf -> v_exp_f32
__device__ __forceinline__ float phi(float x) {
    return x > 0.0f ? x + 1.0f : __expf(x);
}

// ---------------- kernel 1: per-chunk aggregates (order-free) ----------------
// MLP-first structure: all loads for a half-chunk (16 float4) issued before any
// consumption; mask loaded once per wave (1 dword/lane) and distributed by shuffle.
__global__ __launch_bounds__(256, 4) void partials_kernel(
    const float* __restrict__ k, const float* __restrict__ v,
    const float* __restrict__ mask,
    float* __restrict__ pk, float* __restrict__ pkv)
{
    const int wave = blockIdx.x * WPB + (threadIdx.x >> 6);
    const int lane = threadIdx.x & 63;
    const int rg = lane >> 4;          // row group 0..3
    const int dg = lane & 15;          // dims [4*dg, 4*dg+4)
    const int bh = wave / CPB;
    const int c  = wave % CPB;
    const int b  = bh / Hn;
    const int l0 = c * CHUNK;

    // one mask row per lane for the whole 64-row chunk
    const float mlane = mask[(size_t)b * Lseq + l0 + lane];
    const size_t rowbase = ((size_t)bh * Lseq + l0 + rg) * Dd + dg * 4;

    float4 ak  = make_float4(0.f, 0.f, 0.f, 0.f);
    float4 akv = make_float4(0.f, 0.f, 0.f, 0.f);

    #pragma unroll
    for (int h = 0; h < 2; ++h) {
        float4 K[8], V[8];
        #pragma unroll
        for (int t = 0; t < 8; ++t) {
            const size_t off = rowbase + (size_t)((h * 8 + t) * 4) * Dd;
            K[t] = *(const float4*)(k + off);
            V[t] = *(const float4*)(v + off);
        }
        #pragma unroll
        for (int t = 0; t < 8; ++t) {
            const float m = __shfl(mlane, (h * 8 + t) * 4 + rg, 64);
            float x;
            x = phi(K[t].x) * m; ak.x += x; akv.x += x * (V[t].x * m);
            x = phi(K[t].y) * m; ak.y += x; akv.y += x * (V[t].y * m);
            x = phi(K[t].z) * m; ak.z += x; akv.z += x * (V[t].z * m);
            x = phi(K[t].w) * m; ak.w += x; akv.w += x * (V[t].w * m);
        }
    }

    // reduce across the 4 row groups — butterfly (xor 16, 32)
    #pragma unroll
    for (int o = 16; o <= 32; o <<= 1) {
        ak.x  += __shfl_xor(ak.x,  o, 64);
        ak.y  += __shfl_xor(ak.y,  o, 64);
        ak.z  += __shfl_xor(ak.z,  o, 64);
        ak.w  += __shfl_xor(ak.w,  o, 64);
        akv.x += __shfl_xor(akv.x, o, 64);
        akv.y += __shfl_xor(akv.y, o, 64);
        akv.z += __shfl_xor(akv.z, o, 64);
        akv.w += __shfl_xor(akv.w, o, 64);
    }

    if (rg == 0) {
        const size_t o = (size_t)wave * Dd + dg * 4;
        *(float4*)(pk  + o) = ak;
        *(float4*)(pkv + o) = akv;
    }
}

// ------------- kernel 2: exclusive scan over chunk aggregates ---------------
__global__ __launch_bounds__(256) void scan_kernel(
    float* __restrict__ pk, float* __restrict__ pkv)
{
    const int bh = blockIdx.x;
    const int d  = threadIdx.x & 63;
    const int qc = threadIdx.x >> 6;       // 0..3
    const size_t base = ((size_t)bh * CPB + qc * QCH) * Dd + d;

    float vk[QCH], vkv[QCH];
    #pragma unroll
    for (int j = 0; j < QCH; ++j) {
        vk[j]  = pk [base + (size_t)j * Dd];
        vkv[j] = pkv[base + (size_t)j * Dd];
    }

    float sk = 0.f, skv = 0.f;
    #pragma unroll
    for (int j = 0; j < QCH; ++j) {
        const float tk = vk[j], tkv = vkv[j];
        vk[j] = sk;   sk  += tk;
        vkv[j] = skv; skv += tkv;
    }

    __shared__ float tK[4][64], tKV[4][64];
    tK[qc][d] = sk; tKV[qc][d] = skv;
    __syncthreads();
    float offk = 0.f, offkv = 0.f;
    #pragma unroll
    for (int t = 0; t < 3; ++t) {
        if (t < qc) { offk += tK[t][d]; offkv += tKV[t][d]; }
    }

    #pragma unroll
    for (int j = 0; j < QCH; ++j) {
        pk [base + (size_t)j * Dd] = vk[j]  + offk;
        pkv[base + (size_t)j * Dd] = vkv[j] + offkv;
    }
}

// ---------------- kernel 3: final pass with exact inclusive prefix -----------
// Loads for 4 quad-rows (12 float4) batched ahead of the serial scan chain.
__global__ __launch_bounds__(256, 4) void final_kernel(
    const float* __restrict__ q, const float* __restrict__ k,
    const float* __restrict__ v, const float* __restrict__ mask,
    const float* __restrict__ pk, const float* __restrict__ pkv,
    float* __restrict__ out)
{
    const int wave = blockIdx.x * WPB + (threadIdx.x >> 6);
    const int lane = threadIdx.x & 63;
    const int rg = lane >> 4;
    const int dg = lane & 15;
    const int bh = wave / CPB;
    const int c  = wave % CPB;
    const int b  = bh / Hn;
    const int l0 = c * CHUNK;

    const float mlane = mask[(size_t)b * Lseq + l0 + lane];
    const size_t rowbase = ((size_t)bh * Lseq + l0 + rg) * Dd + dg * 4;

    const size_t po = (size_t)wave * Dd + dg * 4;
    float4 Sk  = *(const float4*)(pk  + po);   // exclusive prefix for this chunk
    float4 Skv = *(const float4*)(pkv + po);

    #pragma unroll
    for (int h = 0; h < 4; ++h) {
        float4 Q[4], K[4], V[4];
        #pragma unroll
        for (int t = 0; t < 4; ++t) {
            const size_t off = rowbase + (size_t)((h * 4 + t) * 4) * Dd;
            Q[t] = *(const float4*)(q + off);
            K[t] = *(const float4*)(k + off);
            V[t] = *(const float4*)(v + off);
        }
        #pragma unroll
        for (int t = 0; t < 4; ++t) {
            const int qd = h * 4 + t;                       // quad-row 0..15
            const float m = __shfl(mlane, qd * 4 + rg, 64);
            const size_t off = rowbase + (size_t)(qd * 4) * Dd;

            float4 fq, a, av;
            fq.x = phi(Q[t].x); fq.y = phi(Q[t].y); fq.z = phi(Q[t].z); fq.w = phi(Q[t].w);
            a.x = phi(K[t].x) * m; av.x = a.x * (V[t].x * m);
            a.y = phi(K[t].y) * m; av.y = a.y * (V[t].y * m);
            a.z = phi(K[t].z) * m; av.z = a.z * (V[t].z * m);
            a.w = phi(K[t].w) * m; av.w = a.w * (V[t].w * m);

            // inclusive scan across the 4 row groups (strides 16, 32)
            float x;
            x = __shfl_up(a.x,  16, 64); if (rg >= 1) a.x  += x;
            x = __shfl_up(a.y,  16, 64); if (rg >= 1) a.y  += x;
            x = __shfl_up(a.z,  16, 64); if (rg >= 1) a.z  += x;
            x = __shfl_up(a.w,  16, 64); if (rg >= 1) a.w  += x;
            x = __shfl_up(av.x, 16, 64); if (rg >= 1) av.x += x;
            x = __shfl_up(av.y, 16, 64); if (rg >= 1) av.y += x;
            x = __shfl_up(av.z, 16, 64); if (rg >= 1) av.z += x;
            x = __shfl_up(av.w, 16, 64); if (rg >= 1) av.w += x;
            x = __shfl_up(a.x,  32, 64); if (rg >= 2) a.x  += x;
            x = __shfl_up(a.y,  32, 64); if (rg >= 2) a.y  += x;
            x = __shfl_up(a.z,  32, 64); if (rg >= 2) a.z  += x;
            x = __shfl_up(a.w,  32, 64); if (rg >= 2) a.w  += x;
            x = __shfl_up(av.x, 32, 64); if (rg >= 2) av.x += x;
            x = __shfl_up(av.y, 32, 64); if (rg >= 2) av.y += x;
            x = __shfl_up(av.z, 32, 64); if (rg >= 2) av.z += x;
            x = __shfl_up(av.w, 32, 64); if (rg >= 2) av.w += x;

            const float4 ik  = make_float4(Sk.x + a.x,   Sk.y + a.y,   Sk.z + a.z,   Sk.w + a.w);
            const float4 ikv = make_float4(Skv.x + av.x, Skv.y + av.y, Skv.z + av.z, Skv.w + av.w);

            // z = (sum_d phi(q)*k_cumsum + EPS) * mask (reduce over 16 dg lanes)
            float p = fq.x * ik.x + fq.y * ik.y + fq.z * ik.z + fq.w * ik.w;
            p += __shfl_xor(p, 1, 64);
            p += __shfl_xor(p, 2, 64);
            p += __shfl_xor(p, 4, 64);
            p += __shfl_xor(p, 8, 64);
            const float z = (p + EPS) * m;
            const float inv = 1.0f / z;

            float4 o4;
            o4.x = fq.x * ikv.x * inv;
            o4.y = fq.y * ikv.y * inv;
            o4.z = fq.z * ikv.z * inv;
            o4.w = fq.w * ikv.w * inv;
            *(float4*)(out + off) = o4;

            // advance running prefix by this quad's total (value at rg==3)
            Sk.x  += __shfl(a.x,  48 + dg, 64);
            Sk.y  += __shfl(a.y,  48 + dg, 64);
            Sk.z  += __shfl(a.z,  48 + dg, 64);
            Sk.w  += __shfl(a.w,  48 + dg, 64);
            Skv.x += __shfl(av.x, 48 + dg, 64);
            Skv.y += __shfl(av.y, 48 + dg, 64);
            Skv.z += __shfl(av.z, 48 + dg, 64);
            Skv.w += __shfl(av.w, 48 + dg, 64);
        }
    }
}

extern "C" void kernel_launch(void* const* d_in, const int* in_sizes, int n_in,
                              void* d_out, int out_size, void* d_ws, size_t ws_size,
                              hipStream_t stream) {
    const float* q    = (const float*)d_in[0];
    const float* k    = (const float*)d_in[1];
    const float* v    = (const float*)d_in[2];
    const float* mask = (const float*)d_in[3];
    float* out = (float*)d_out;

    float* pk  = (float*)d_ws;
    float* pkv = pk + (size_t)NCHUNKS * Dd;

    partials_kernel<<<NBLK, 256, 0, stream>>>(k, v, mask, pk, pkv);
    scan_kernel<<<BH, 256, 0, stream>>>(pk, pkv);
    final_kernel<<<NBLK, 256, 0, stream>>>(q, k, v, mask, pk, pkv, out);
}